// Round 1
// baseline (655.887 us; speedup 1.0000x reference)
//
#include <hip/hip_runtime.h>
#include <stdint.h>

typedef unsigned long long u64;

// Problem constants
#define NB   16
#define NT   12
#define BTc  192     // NB*NT
#define NN   4096
#define DD   64
#define MM   128
#define TOPK 32

// d_out float offsets (outputs concatenated flat, all read back as float32)
#define SEL1_OFF 0ULL
#define SEL2_OFF 50331648ULL
#define BIDX_OFF 100663296ULL
#define TIDX_OFF 101449728ULL
#define IDX_OFF  102236160ULL

__device__ __forceinline__ unsigned ord32(float f) {
    unsigned u = __float_as_uint(f);
    return (u & 0x80000000u) ? ~u : (u | 0x80000000u);
}

// ---------------------------------------------------------------------------
// K1: logits[bt][m][n] = sum_k emb[m][k] * nv3[bt][n][k]   (fp32, seq-k FMA)
// grid: (32 n-tiles, 192 bt), block 256. Tile: 128m x 128n x 32k.
// ---------------------------------------------------------------------------
__global__ __launch_bounds__(256) void k1_logits(const float* __restrict__ nv1,
                                                 const float* __restrict__ nv2,
                                                 const float* __restrict__ emb,
                                                 float* __restrict__ logits) {
    const int nt  = blockIdx.x;   // 0..31
    const int bt  = blockIdx.y;   // 0..191
    const int tid = threadIdx.x;
    const int n0  = nt * 128;

    __shared__ float Als[32][132];  // [k][m]
    __shared__ float Bls[32][132];  // [k][n]

    const int tm = tid >> 4;   // 0..15
    const int tn = tid & 15;   // 0..15

    float acc[8][8];
#pragma unroll
    for (int i = 0; i < 8; ++i)
#pragma unroll
        for (int j = 0; j < 8; ++j) acc[i][j] = 0.0f;

    for (int k0 = 0; k0 < 128; k0 += 32) {
        // Stage A: emb rows (128 x 32k), 1024 float4s across 256 threads
#pragma unroll
        for (int it = 0; it < 4; ++it) {
            int f4  = it * 256 + tid;
            int row = f4 >> 3;       // m
            int kq  = f4 & 7;        // float4 within 32-float k segment
            float4 a = *(const float4*)(emb + row * 128 + k0 + kq * 4);
            Als[kq * 4 + 0][row] = a.x;
            Als[kq * 4 + 1][row] = a.y;
            Als[kq * 4 + 2][row] = a.z;
            Als[kq * 4 + 3][row] = a.w;
        }
        // Stage B: nv3 rows (128 x 32k): k<64 -> nv1, else nv2
#pragma unroll
        for (int it = 0; it < 4; ++it) {
            int f4  = it * 256 + tid;
            int row = f4 >> 3;       // n within tile
            int kq  = f4 & 7;
            const float* src = (k0 < 64)
                ? (nv1 + ((size_t)bt * NN + n0 + row) * DD + k0 + kq * 4)
                : (nv2 + ((size_t)bt * NN + n0 + row) * DD + (k0 - 64) + kq * 4);
            float4 b = *(const float4*)src;
            Bls[kq * 4 + 0][row] = b.x;
            Bls[kq * 4 + 1][row] = b.y;
            Bls[kq * 4 + 2][row] = b.z;
            Bls[kq * 4 + 3][row] = b.w;
        }
        __syncthreads();

#pragma unroll 8
        for (int kk = 0; kk < 32; ++kk) {
            float4 a0 = *(const float4*)&Als[kk][tm * 8];
            float4 a1 = *(const float4*)&Als[kk][tm * 8 + 4];
            float4 b0 = *(const float4*)&Bls[kk][tn * 8];
            float4 b1 = *(const float4*)&Bls[kk][tn * 8 + 4];
            float av[8] = {a0.x, a0.y, a0.z, a0.w, a1.x, a1.y, a1.z, a1.w};
            float bv[8] = {b0.x, b0.y, b0.z, b0.w, b1.x, b1.y, b1.z, b1.w};
#pragma unroll
            for (int i = 0; i < 8; ++i)
#pragma unroll
                for (int j = 0; j < 8; ++j)
                    acc[i][j] = fmaf(av[i], bv[j], acc[i][j]);
        }
        __syncthreads();
    }

    // Write C
#pragma unroll
    for (int i = 0; i < 8; ++i) {
        size_t base = ((size_t)bt * MM + tm * 8 + i) * NN + n0 + tn * 8;
        float4 c0 = {acc[i][0], acc[i][1], acc[i][2], acc[i][3]};
        float4 c1 = {acc[i][4], acc[i][5], acc[i][6], acc[i][7]};
        *(float4*)(logits + base)     = c0;
        *(float4*)(logits + base + 4) = c1;
    }
}

// ---------------------------------------------------------------------------
// K2: exact top-32 (desc, ties -> lower index) per row of 4096 logits.
// One wave per row; block 256 = 4 rows. Writes indices/batch/time as floats.
// ---------------------------------------------------------------------------
__global__ __launch_bounds__(256) void k2_topk(const float* __restrict__ logits,
                                               float* out) {
    const int tid  = threadIdx.x;
    const int lane = tid & 63;
    const int w    = tid >> 6;
    const int row  = blockIdx.x * 4 + w;   // 0..24575
    const int bt   = row >> 7;
    const float* src = logits + (size_t)row * NN;

    __shared__ u64 buf[4][256];

    // Pass A: per-lane max over its 64 elements (coalesced float4)
    float lmax = -INFINITY;
#pragma unroll
    for (int j = 0; j < 16; ++j) {
        float4 v = *(const float4*)(src + j * 256 + lane * 4);
        lmax = fmaxf(lmax, fmaxf(fmaxf(v.x, v.y), fmaxf(v.z, v.w)));
    }

    // Bitonic sort-64 of lane maxima, descending across lanes
    float v = lmax;
#pragma unroll
    for (int k = 2; k <= 64; k <<= 1) {
#pragma unroll
        for (int j = k >> 1; j >= 1; j >>= 1) {
            float o = __shfl_xor(v, j);
            bool lower = (lane & j) == 0;
            bool descBlock = (lane & k) == 0;
            bool takeMax = (lower == descBlock);
            v = takeMax ? fmaxf(v, o) : fminf(v, o);
        }
    }
    const float T0 = __shfl(v, 31);  // 32nd largest lane-max: guarantees >=32 elems >= T0

    // Pass B: compact candidates (val >= T0) into LDS buffer
    int c = 0;
    for (int j = 0; j < 16; ++j) {
        float4 q = *(const float4*)(src + j * 256 + lane * 4);
        int nb = j * 256 + lane * 4;
        float qv[4] = {q.x, q.y, q.z, q.w};
#pragma unroll
        for (int e = 0; e < 4; ++e) {
            bool p = (qv[e] >= T0);
            u64 mask = __ballot(p);
            if (p) {
                int pos = c + (int)__popcll(mask & ((1ull << lane) - 1ull));
                if (pos < 256) {
                    u64 key = ((u64)ord32(qv[e]) << 32) |
                              (u64)(0xFFFFFFFFu - (unsigned)(nb + e));
                    buf[w][pos] = key;
                }
            }
            c += (int)__popcll(mask);
        }
    }
    if (c > 256) c = 256;
    // Pad remainder with 0 (never selected: real keys have nonzero high bits)
    for (int i = c + lane; i < 256; i += 64) buf[w][i] = 0ull;

    u64 kreg[4];
#pragma unroll
    for (int r = 0; r < 4; ++r) kreg[r] = buf[w][lane + 64 * r];

    const int b = bt / NT;
    const int t = bt - b * NT;
    const size_t obase = (size_t)row * TOPK;

    for (int p = 0; p < TOPK; ++p) {
        u64 best = kreg[0];
        if (kreg[1] > best) best = kreg[1];
        if (kreg[2] > best) best = kreg[2];
        if (kreg[3] > best) best = kreg[3];
#pragma unroll
        for (int j = 1; j < 64; j <<= 1) {
            u64 o = __shfl_xor(best, j);
            if (o > best) best = o;
        }
        unsigned node = 0xFFFFFFFFu - (unsigned)(best & 0xFFFFFFFFull);
        if (lane == 0) {
            out[IDX_OFF  + obase + p] = (float)node;
            out[BIDX_OFF + obase + p] = (float)b;
            out[TIDX_OFF + obase + p] = (float)t;
        }
#pragma unroll
        for (int r = 0; r < 4; ++r)
            if (kreg[r] == best) kreg[r] = 0ull;
    }
}

// ---------------------------------------------------------------------------
// K3: gather sel1/sel2 rows per selected index. One float4 per thread per sel.
// Overwrites the logits scratch region (nothing reads it anymore).
// ---------------------------------------------------------------------------
__global__ __launch_bounds__(256) void k3_gather(const float* __restrict__ nv1,
                                                 const float* __restrict__ nv2,
                                                 float* out) {
    int g  = blockIdx.x * 256 + threadIdx.x;
    int d4 = g & 15;
    int k  = (g >> 4) & 31;
    int r  = g >> 9;             // row (bt*128 + m), 0..24575
    int bt = r >> 7;
    int idx = (int)out[IDX_OFF + (size_t)r * TOPK + k];
    idx &= (NN - 1);             // safety clamp
    const float4 s1 = *(const float4*)(nv1 + ((size_t)bt * NN + idx) * DD + d4 * 4);
    const float4 s2 = *(const float4*)(nv2 + ((size_t)bt * NN + idx) * DD + d4 * 4);
    size_t o = ((size_t)r * TOPK + k) * DD + d4 * 4;
    *(float4*)(out + SEL1_OFF + o) = s1;
    *(float4*)(out + SEL2_OFF + o) = s2;
}

extern "C" void kernel_launch(void* const* d_in, const int* in_sizes, int n_in,
                              void* d_out, int out_size, void* d_ws, size_t ws_size,
                              hipStream_t stream) {
    const float* nv1 = (const float*)d_in[0];
    const float* nv2 = (const float*)d_in[1];
    const float* emb = (const float*)d_in[2];
    float* out = (float*)d_out;

    dim3 g1(32, BTc);
    k1_logits<<<g1, 256, 0, stream>>>(nv1, nv2, emb, out);
    k2_topk<<<24576 / 4, 256, 0, stream>>>(out, out);
    k3_gather<<<(24576 * TOPK * 16) / 256, 256, 0, stream>>>(nv1, nv2, out);
}

// Round 2
// 586.444 us; speedup vs baseline: 1.1184x; 1.1184x over previous
//
#include <hip/hip_runtime.h>
#include <stdint.h>

typedef unsigned long long u64;
typedef unsigned short u16;
typedef __attribute__((ext_vector_type(8))) short short8;
typedef __attribute__((ext_vector_type(4))) float f32x4;

// Problem constants
#define NB   16
#define NT   12
#define BTc  192     // NB*NT
#define NN   4096
#define DD   64
#define MM   128
#define TOPK 32
#define CAP  192     // candidate capacity per row (expected ~70)

// d_out float offsets (outputs concatenated flat)
#define SEL1_OFF 0ULL
#define SEL2_OFF 50331648ULL
#define BIDX_OFF 100663296ULL
#define TIDX_OFF 101449728ULL
#define IDX_OFF  102236160ULL
// bf16 logits scratch: 24576*4096 u16 = 201 MB, occupies float region [0, 50331648) == SEL1 region.
// K2 consumes it before K3 overwrites with sel1.

__device__ __forceinline__ unsigned ord32(float f) {
    unsigned u = __float_as_uint(f);
    return (u & 0x80000000u) ? ~u : (u | 0x80000000u);
}
__device__ __forceinline__ u16 f2bf(float f) {   // RNE round to bf16
    unsigned u = __float_as_uint(f);
    unsigned r = u + 0x7FFFu + ((u >> 16) & 1u);
    return (u16)(r >> 16);
}
__device__ __forceinline__ float bf2f(short s) {
    return __uint_as_float(((unsigned)(u16)s) << 16);
}
__device__ __forceinline__ u64 pack4bf(float4 v) {
    return (u64)f2bf(v.x) | ((u64)f2bf(v.y) << 16) |
           ((u64)f2bf(v.z) << 32) | ((u64)f2bf(v.w) << 48);
}

// ---------------------------------------------------------------------------
// K1: approx logits via bf16 MFMA. Tile 128m x 128n, full K=128 single-shot.
// LDS layout: row-major [row][128 bf16] with byte ^= ((row&7)<<4) XOR swizzle
// (G4) so frag ds_read_b128 (16 lanes, different rows, same k-slice) is 2-way.
// grid (32 n-tiles, 192 bt), block 256 (4 waves; wave -> 64m x 64n quadrant).
// ---------------------------------------------------------------------------
__global__ __launch_bounds__(256) void k1_logits_bf16(const float* __restrict__ nv1,
                                                      const float* __restrict__ nv2,
                                                      const float* __restrict__ emb,
                                                      u16* __restrict__ logitsB) {
    __shared__ u16 Als[128 * 128];   // 32 KB, [m][k] swizzled
    __shared__ u16 Bls[128 * 128];   // 32 KB, [n][k] swizzled (B^T layout)

    const int tid = threadIdx.x;
    const int nt  = blockIdx.x;      // 0..31
    const int bt  = blockIdx.y;      // 0..191
    const int n0  = nt * 128;

    // Stage A: emb 128x128 fp32 -> bf16 (4096 float4s, 16 per thread)
#pragma unroll
    for (int it = 0; it < 16; ++it) {
        int f4  = it * 256 + tid;
        int row = f4 >> 5;           // m
        int kq  = f4 & 31;           // float4 within row
        float4 a = *(const float4*)(emb + row * 128 + kq * 4);
        int byte = row * 256 + ((kq * 8) ^ ((row & 7) << 4));
        *(u64*)((char*)Als + byte) = pack4bf(a);
    }
    // Stage B: nv3 tile rows (k<64 from nv1, else nv2)
#pragma unroll
    for (int it = 0; it < 16; ++it) {
        int f4  = it * 256 + tid;
        int row = f4 >> 5;           // n within tile
        int kq  = f4 & 31;
        const float* src = (kq < 16)
            ? (nv1 + ((size_t)bt * NN + n0 + row) * DD + kq * 4)
            : (nv2 + ((size_t)bt * NN + n0 + row) * DD + (kq - 16) * 4);
        float4 bv = *(const float4*)src;
        int byte = row * 256 + ((kq * 8) ^ ((row & 7) << 4));
        *(u64*)((char*)Bls + byte) = pack4bf(bv);
    }
    __syncthreads();

    const int w  = tid >> 6;
    const int l  = tid & 63;
    const int mb = (w >> 1) * 64;
    const int nb = (w & 1) * 64;
    const int xr = (l & 7) << 4;     // row&7 == l&7 for all fragments (16-aligned bases)

    f32x4 acc[4][4];
#pragma unroll
    for (int mi = 0; mi < 4; ++mi)
#pragma unroll
        for (int ni = 0; ni < 4; ++ni) acc[mi][ni] = {0.f, 0.f, 0.f, 0.f};

#pragma unroll
    for (int ks = 0; ks < 4; ++ks) {
        const int kb = (ks * 64 + (l >> 4) * 16) ^ xr;
        short8 a[4], b[4];
#pragma unroll
        for (int mi = 0; mi < 4; ++mi) {
            int row = mb + mi * 16 + (l & 15);
            a[mi] = *(const short8*)((const char*)Als + row * 256 + kb);
        }
#pragma unroll
        for (int ni = 0; ni < 4; ++ni) {
            int row = nb + ni * 16 + (l & 15);
            b[ni] = *(const short8*)((const char*)Bls + row * 256 + kb);
        }
#pragma unroll
        for (int mi = 0; mi < 4; ++mi)
#pragma unroll
            for (int ni = 0; ni < 4; ++ni)
                acc[mi][ni] = __builtin_amdgcn_mfma_f32_16x16x32_bf16(
                    a[mi], b[ni], acc[mi][ni], 0, 0, 0);
    }

    // Store approx logits as bf16. C/D: col = lane&15, row = (lane>>4)*4 + reg.
    const size_t rbase = (size_t)bt * MM * NN;
#pragma unroll
    for (int mi = 0; mi < 4; ++mi)
#pragma unroll
        for (int ni = 0; ni < 4; ++ni) {
            int n = n0 + nb + ni * 16 + (l & 15);
#pragma unroll
            for (int r = 0; r < 4; ++r) {
                int m = mb + mi * 16 + (l >> 4) * 4 + r;
                logitsB[rbase + (size_t)m * NN + n] = f2bf(acc[mi][ni][r]);
            }
        }
}

// ---------------------------------------------------------------------------
// K2: per row — approx top-48 superset from bf16 logits, exact fp32 recompute
// of candidates (identical seq-k fmaf order as the verified round-1 kernel),
// exact rank top-32 (desc, ties -> lower index). One wave per row.
// ---------------------------------------------------------------------------
__global__ __launch_bounds__(256) void k2_topk(const u16* __restrict__ logitsB,
                                               const float* __restrict__ nv1,
                                               const float* __restrict__ nv2,
                                               const float* __restrict__ emb,
                                               float* out) {
    const int tid = threadIdx.x;
    const int l   = tid & 63;
    const int w   = tid >> 6;
    const int row = blockIdx.x * 4 + w;   // 0..24575
    const int bt  = row >> 7;
    const int m   = row & 127;
    const u16* src = logitsB + (size_t)row * NN;

    __shared__ int   cand[4][CAP];
    __shared__ float embrow[4][128];

    embrow[w][l]      = emb[m * 128 + l];
    embrow[w][l + 64] = emb[m * 128 + 64 + l];

    // Load row (64 bf16 per lane, kept in regs) + lane max
    short8 ch[8];
    float lmax = -INFINITY;
#pragma unroll
    for (int j = 0; j < 8; ++j) {
        ch[j] = *(const short8*)(src + j * 512 + l * 8);
#pragma unroll
        for (int e = 0; e < 8; ++e) lmax = fmaxf(lmax, bf2f(ch[j][e]));
    }

    // Bitonic sort-64 of lane maxima, descending
    float v = lmax;
#pragma unroll
    for (int k = 2; k <= 64; k <<= 1) {
#pragma unroll
        for (int j = k >> 1; j >= 1; j >>= 1) {
            float o = __shfl_xor(v, j);
            bool lower = (l & j) == 0;
            bool descB = (l & k) == 0;
            v = (lower == descB) ? fmaxf(v, o) : fminf(v, o);
        }
    }
    const float T = __shfl(v, 47);   // 48th-largest lane-max => >=48 elems >= T

    // Compact candidate indices (approx val >= T)
    int c = 0;
#pragma unroll
    for (int j = 0; j < 8; ++j) {
#pragma unroll
        for (int e = 0; e < 8; ++e) {
            bool p = (bf2f(ch[j][e]) >= T);
            u64 mask = __ballot(p);
            if (p) {
                int pos = c + (int)__popcll(mask & ((1ull << l) - 1ull));
                if (pos < CAP) cand[w][pos] = j * 512 + l * 8 + e;
            }
            c += (int)__popcll(mask);
        }
    }
    if (c > CAP) c = CAP;
    __syncthreads();

    // Exact fp32 recompute (seq k=0..127 fmaf — bit-identical to round-1 K1)
    u64 kreg[3];
#pragma unroll
    for (int s3 = 0; s3 < 3; ++s3) {
        int s = s3 * 64 + l;
        u64 key = 0ull;
        if (s < c) {
            int n = cand[w][s];
            const float4* c1 = (const float4*)(nv1 + ((size_t)bt * NN + n) * DD);
            const float4* c2 = (const float4*)(nv2 + ((size_t)bt * NN + n) * DD);
            float acc = 0.f;
#pragma unroll
            for (int q = 0; q < 16; ++q) {
                float4 x = c1[q];
                acc = fmaf(embrow[w][q * 4 + 0], x.x, acc);
                acc = fmaf(embrow[w][q * 4 + 1], x.y, acc);
                acc = fmaf(embrow[w][q * 4 + 2], x.z, acc);
                acc = fmaf(embrow[w][q * 4 + 3], x.w, acc);
            }
#pragma unroll
            for (int q = 0; q < 16; ++q) {
                float4 x = c2[q];
                acc = fmaf(embrow[w][64 + q * 4 + 0], x.x, acc);
                acc = fmaf(embrow[w][64 + q * 4 + 1], x.y, acc);
                acc = fmaf(embrow[w][64 + q * 4 + 2], x.z, acc);
                acc = fmaf(embrow[w][64 + q * 4 + 3], x.w, acc);
            }
            key = ((u64)ord32(acc) << 32) | (u64)(0xFFFFFFFFu - (unsigned)n);
        }
        kreg[s3] = key;
    }

    // Pop exact top-32
    const int b = bt / NT;
    const int t = bt - b * NT;
    const size_t obase = (size_t)row * TOPK;
    for (int p = 0; p < TOPK; ++p) {
        u64 best = kreg[0];
        if (kreg[1] > best) best = kreg[1];
        if (kreg[2] > best) best = kreg[2];
#pragma unroll
        for (int j = 1; j < 64; j <<= 1) {
            u64 o = __shfl_xor(best, j);
            if (o > best) best = o;
        }
        unsigned node = 0xFFFFFFFFu - (unsigned)(best & 0xFFFFFFFFull);
        if (l == 0) {
            out[IDX_OFF  + obase + p] = (float)node;
            out[BIDX_OFF + obase + p] = (float)b;
            out[TIDX_OFF + obase + p] = (float)t;
        }
#pragma unroll
        for (int r = 0; r < 3; ++r)
            if (kreg[r] == best) kreg[r] = 0ull;
    }
}

// ---------------------------------------------------------------------------
// K3: gather sel1/sel2 rows per selected index. Overwrites logits scratch.
// ---------------------------------------------------------------------------
__global__ __launch_bounds__(256) void k3_gather(const float* __restrict__ nv1,
                                                 const float* __restrict__ nv2,
                                                 float* out) {
    int g  = blockIdx.x * 256 + threadIdx.x;
    int d4 = g & 15;
    int k  = (g >> 4) & 31;
    int r  = g >> 9;             // row (bt*128 + m)
    int bt = r >> 7;
    int idx = (int)out[IDX_OFF + (size_t)r * TOPK + k];
    idx &= (NN - 1);             // safety clamp
    const float4 s1 = *(const float4*)(nv1 + ((size_t)bt * NN + idx) * DD + d4 * 4);
    const float4 s2 = *(const float4*)(nv2 + ((size_t)bt * NN + idx) * DD + d4 * 4);
    size_t o = ((size_t)r * TOPK + k) * DD + d4 * 4;
    *(float4*)(out + SEL1_OFF + o) = s1;
    *(float4*)(out + SEL2_OFF + o) = s2;
}

extern "C" void kernel_launch(void* const* d_in, const int* in_sizes, int n_in,
                              void* d_out, int out_size, void* d_ws, size_t ws_size,
                              hipStream_t stream) {
    const float* nv1 = (const float*)d_in[0];
    const float* nv2 = (const float*)d_in[1];
    const float* emb = (const float*)d_in[2];
    float* out = (float*)d_out;

    dim3 g1(32, BTc);
    k1_logits_bf16<<<g1, 256, 0, stream>>>(nv1, nv2, emb, (u16*)d_out);
    k2_topk<<<24576 / 4, 256, 0, stream>>>((const u16*)d_out, nv1, nv2, emb, out);
    k3_gather<<<(24576 * TOPK * 16) / 256, 256, 0, stream>>>(nv1, nv2, out);
}